// Round 3
// baseline (175.618 us; speedup 1.0000x reference)
//
#include <hip/hip_runtime.h>
#include <hip/hip_bf16.h>

// B=8, S=128, E=50, D=300, DE=50, F=750 — ALL I/O IS FLOAT32.
// out: node[307200] floats, then edge[6553600] floats.
// ws (floats): R1[51200] | R2[51200]

typedef __bf16 bf16x8 __attribute__((ext_vector_type(8)));
typedef float f32x4 __attribute__((ext_vector_type(4)));

__device__ __forceinline__ unsigned short f2bf(float f) {
    __hip_bfloat16 h = __float2bfloat16(f);      // round-to-nearest
    union { __hip_bfloat16 h; unsigned short u; } c; c.h = h; return c.u;
}

// ---------------- K1: fused  M = mean_e(wps)+I ; Axm = M@x ; h = Axm@Ww + Wb ;
// ---------------- LayerNorm(unbiased std, +eps on std)+relu -> node_out (fp32)
// one block = 4 consecutive rows (b, i..i+3); 320 threads (300 active cols)
__global__ void __launch_bounds__(320) k_node(
    const float* __restrict__ wps,
    const float* __restrict__ x,
    const float* __restrict__ Ww,
    const float* __restrict__ Wb,
    const float* __restrict__ lna,
    const float* __restrict__ lnb,
    float* __restrict__ node_out)
{
    __shared__ float Ml[4][128];
    __shared__ float axm[4][304];
    __shared__ float hl[4][304];
    __shared__ float stats[8];
    int tid = threadIdx.x;
    int b = blockIdx.x >> 5;
    int ig = blockIdx.x & 31;
    int row0 = b * 128 + ig * 4;   // global (b*S + i) base

    // fused msum: M[r][j] = (1/E) * sum_e wps[b, i0+r, j, e] + ((i0+r)==j)
    for (int slot = tid; slot < 512; slot += 320) {
        int r = slot >> 7, j = slot & 127;
        const float2* p = (const float2*)(wps + ((size_t)(row0 + r) * 128 + j) * 50);
        float s = 0.f;
#pragma unroll
        for (int n = 0; n < 25; ++n) { float2 v = p[n]; s += v.x + v.y; }
        Ml[r][j] = s * (1.0f / 50.0f) + (((ig * 4 + r) == j) ? 1.0f : 0.0f);
    }
    __syncthreads();

    if (tid < 300) {
        float a0 = 0.f, a1 = 0.f, a2 = 0.f, a3 = 0.f;
        const float* xp = x + (size_t)b * (128 * 300) + tid;
        for (int j = 0; j < 128; ++j) {
            float xv = xp[j * 300];
            a0 += Ml[0][j] * xv; a1 += Ml[1][j] * xv;
            a2 += Ml[2][j] * xv; a3 += Ml[3][j] * xv;
        }
        axm[0][tid] = a0; axm[1][tid] = a1; axm[2][tid] = a2; axm[3][tid] = a3;
    }
    __syncthreads();

    if (tid < 300) {
        float wb = Wb[tid];
        float h0 = wb, h1 = wb, h2 = wb, h3 = wb;
        const float* wp = Ww + tid;
        for (int k = 0; k < 300; ++k) {
            float w = wp[k * 300];
            h0 += axm[0][k] * w; h1 += axm[1][k] * w;
            h2 += axm[2][k] * w; h3 += axm[3][k] * w;
        }
        hl[0][tid] = h0; hl[1][tid] = h1; hl[2][tid] = h2; hl[3][tid] = h3;
    }
    __syncthreads();

    int wv = tid >> 6;
    if (wv < 4) {
        int lane = tid & 63;
        float s1 = 0.f, s2 = 0.f;
        for (int dd = lane; dd < 300; dd += 64) {
            float v = hl[wv][dd]; s1 += v; s2 += v * v;
        }
        for (int off = 32; off > 0; off >>= 1) {
            s1 += __shfl_down(s1, off);
            s2 += __shfl_down(s2, off);
        }
        if (lane == 0) {
            float mean = s1 * (1.0f / 300.0f);
            float var = (s2 - 300.0f * mean * mean) * (1.0f / 299.0f);
            var = fmaxf(var, 0.0f);
            stats[wv * 2] = mean;
            stats[wv * 2 + 1] = 1.0f / (sqrtf(var) + 1e-6f);
        }
    }
    __syncthreads();

    if (tid < 300) {
        float la = lna[tid];
        float lb = lnb[tid];
#pragma unroll
        for (int r = 0; r < 4; ++r) {
            float v = la * (hl[r][tid] - stats[r * 2]) * stats[r * 2 + 1] + lb;
            node_out[(size_t)(row0 + r) * 300 + tid] = fmaxf(v, 0.0f);
        }
    }
}

// ---------------- K2: R1[b,s,k], R2[b,s,k] (row-invariant parts of refine) ------
__global__ void k_r12(const float* __restrict__ wa,
                      const float* __restrict__ Rw,
                      const float* __restrict__ rb,
                      const float* __restrict__ node,
                      float* __restrict__ R1, float* __restrict__ R2)
{
    int wv = threadIdx.x >> 6;
    int k = threadIdx.x & 63;
    int row = blockIdx.x * 4 + wv;    // b*S + s
    if (k >= 50) return;
    int b = row >> 7, s = row & 127;
    const float* dp = wa + (((size_t)(b * 128 + s)) * 128 + s) * 50;  // diag
    const float* np = node + (size_t)row * 300;
    float r1 = 0.f, r2 = rb[k];
    for (int e = 0; e < 50; ++e) {
        float de = dp[e];
        r1 += de * Rw[(50 + e) * 50 + k];    // edge_i columns (depend on j)
        r2 += de * Rw[(100 + e) * 50 + k];   // edge_j columns (depend on i)
    }
    for (int d = 0; d < 300; ++d) {
        float nv = np[d];
        r1 += nv * Rw[(150 + d) * 50 + k];   // node1 columns
        r2 += nv * Rw[(450 + d) * 50 + k];   // node2 columns
    }
    R1[row * 50 + k] = r1;
    R2[row * 50 + k] = r2;
}

// ---------------- K3: edge_out[b,i,j,k] = wa[b,i,j,:]·Rw[0:50,k] + R1 + R2 ------
// one block per (b,i): 128x64x64(padded) bf16 MFMA GEMM; fp32 in/out.
__global__ void __launch_bounds__(256) k_edge(
    const float* __restrict__ wa,
    const float* __restrict__ Rw,
    const float* __restrict__ R1, const float* __restrict__ R2,
    float* __restrict__ eout)
{
    __shared__ __align__(16) unsigned short waA[128 * 72];   // A tile (bf16), stride 72
    __shared__ __align__(16) unsigned short rwBT[64 * 72];   // B^T (bf16): rwBT[k][e]=Rw[e][k]
    int tid = threadIdx.x;
    int bi = blockIdx.x;       // b*128 + i
    int b = bi >> 7;

    for (int idx = tid; idx < 2304; idx += 256) ((unsigned int*)rwBT)[idx] = 0u;
    for (int idx = tid; idx < 1408; idx += 256) {          // zero waA pad e in [50,72)
        int j = idx / 11, c = idx % 11;
        *((unsigned int*)(waA + j * 72 + 50) + c) = 0u;
    }
    __syncthreads();

    const float2* wap = (const float2*)(wa + (size_t)bi * 6400);
    for (int idx = tid; idx < 3200; idx += 256) {          // 6400 floats, rows of 50
        float2 v = wap[idx];
        int f = idx * 2;
        int j = f / 50, e = f % 50;                         // e even -> 4B-aligned store
        unsigned int pack = (unsigned int)f2bf(v.x) | ((unsigned int)f2bf(v.y) << 16);
        *(unsigned int*)(waA + j * 72 + e) = pack;
    }
    for (int idx = tid; idx < 2500; idx += 256) {          // transpose+cvt Rw[0:50][0:50]
        int e = idx / 50, kk = idx % 50;
        rwBT[kk * 72 + e] = f2bf(Rw[idx]);
    }
    __syncthreads();

    int lane = tid & 63, wv = tid >> 6;
    int q = lane >> 4, lr = lane & 15;
    f32x4 acc[2][4] = {};

#pragma unroll
    for (int ks = 0; ks < 2; ++ks) {
        int e0 = ks * 32 + q * 8;
        bf16x8 a0 = *(const bf16x8*)&waA[(wv * 32 + lr) * 72 + e0];
        bf16x8 a1 = *(const bf16x8*)&waA[(wv * 32 + 16 + lr) * 72 + e0];
#pragma unroll
        for (int nt = 0; nt < 4; ++nt) {
            bf16x8 bb = *(const bf16x8*)&rwBT[(nt * 16 + lr) * 72 + e0];
            acc[0][nt] = __builtin_amdgcn_mfma_f32_16x16x32_bf16(a0, bb, acc[0][nt], 0, 0, 0);
            acc[1][nt] = __builtin_amdgcn_mfma_f32_16x16x32_bf16(a1, bb, acc[1][nt], 0, 0, 0);
        }
    }

    const float* r2p = R2 + (size_t)bi * 50;
    float* op = eout + (size_t)bi * 6400;
#pragma unroll
    for (int nt = 0; nt < 4; ++nt) {
        int kk = nt * 16 + lr;
        if (kk < 50) {
            float r2v = r2p[kk];
#pragma unroll
            for (int mi = 0; mi < 2; ++mi) {
                int jbase = wv * 32 + mi * 16 + q * 4;
#pragma unroll
                for (int r = 0; r < 4; ++r) {
                    int jj = jbase + r;
                    float v = acc[mi][nt][r] + R1[(size_t)(b * 128 + jj) * 50 + kk] + r2v;
                    op[(size_t)jj * 50 + kk] = v;
                }
            }
        }
    }
}

extern "C" void kernel_launch(void* const* d_in, const int* in_sizes, int n_in,
                              void* d_out, int out_size, void* d_ws, size_t ws_size,
                              hipStream_t stream)
{
    const float* wps = (const float*)d_in[0];
    const float* wa  = (const float*)d_in[1];
    const float* x   = (const float*)d_in[2];
    // d_in[3] self_loop: identity on every channel, folded into k_node (+1 on diag)
    const float* Ww  = (const float*)d_in[4];
    const float* Wb  = (const float*)d_in[5];
    const float* lna = (const float*)d_in[6];
    const float* lnb = (const float*)d_in[7];
    const float* Rw  = (const float*)d_in[8];
    const float* rb  = (const float*)d_in[9];

    float* R1 = (float*)d_ws;            // 51200 floats
    float* R2 = ((float*)d_ws) + 51200;  // 51200 floats

    float* node_out = (float*)d_out;             // 307200 floats
    float* edge_out = node_out + 307200;         // 6553600 floats

    k_node<<<256, 320, 0, stream>>>(wps, x, Ww, Wb, lna, lnb, node_out);
    k_r12 <<<256, 256, 0, stream>>>(wa, Rw, rb, node_out, R1, R2);
    k_edge<<<1024, 256, 0, stream>>>(wa, Rw, R1, R2, edge_out);
}